// Round 7
// baseline (533.076 us; speedup 1.0000x reference)
//
#include <hip/hip_runtime.h>

typedef float __attribute__((ext_vector_type(4))) f32x4;

// ============================================================================
// Round 7: granularity fix. 256 blocks x 1024 thr = 1 block/CU had zero
// work-stealing slack (tail) and CU-wide barrier coupling (gate phase fully
// exposed). Now 1024 blocks x 256 thr (quarter-cubes, ~4-8 blocks/CU):
// tail shrinks 4x, and co-resident blocks hide each other's barrier/gate
// phases. Stage C keeps the A/B-proven R4 form (nt load + nt store, simple
// alternating loop -- R6 showed batching hurts).
// pool layout (f32, in d_ws): [n][l][c]; l: 0..63 = d, 64..127 = h,
// 128..191 = w. Built via global f32 atomics (<=4 contributors/address).
// ============================================================================

// pool = 4*192*64 = 49152 floats; zero before pool_k's atomics.
__global__ __launch_bounds__(1024) void zero_k(float* __restrict__ p) {
    p[blockIdx.x * 1024 + threadIdx.x] = 0.f;
}

// Block b: cube blk = b>>2 (n,c), quarter q = b&3 -> d in [q*16, q*16+16).
// 256 threads = 4 waves. Per (d): 4 coalesced f32x4 reads per thread.
__global__ __launch_bounds__(256) void pool_k(const float* __restrict__ x,
                                              float* __restrict__ pool) {
    const int b   = blockIdx.x;
    const int blk = b >> 2;
    const int q   = b & 3;
    const int n = blk >> 6, c = blk & 63;
    const int d0 = q * 16;
    const int t = threadIdx.x;           // 0..255
    const int w = t >> 6, l = t & 63;    // wave, lane

    __shared__ float sdp[16];
    __shared__ float swp[64];
    if (t < 16) sdp[t] = 0.f;
    if (t < 64) swp[t] = 0.f;
    __syncthreads();

    const f32x4* __restrict__ xp = (const f32x4*)(x + (size_t)blk * 262144);

    float accw[4] = {0,0,0,0};
    float acch[4] = {0,0,0,0};           // per i-chunk: h = i*16 + w*4 + (l>>4)

    for (int dd = 0; dd < 16; ++dd) {
        float sacc = 0.f;
        #pragma unroll
        for (int i = 0; i < 4; ++i) {    // f32x4 group p = i*256 + t
            f32x4 v = xp[(d0 + dd) * 1024 + i * 256 + t];
            accw[0] += v.x; accw[1] += v.y; accw[2] += v.z; accw[3] += v.w;
            float s = (v.x + v.y) + (v.z + v.w);
            sacc += s;
            acch[i] += s;
        }
        // d-mean partial: full-wave reduce, one LDS atomic per wave
        float r = sacc;
        r += __shfl_down(r, 32);
        r += __shfl_down(r, 16);
        r += __shfl_down(r, 8);
        r += __shfl_down(r, 4);
        r += __shfl_down(r, 2);
        r += __shfl_down(r, 1);
        if (l == 0) atomicAdd(&sdp[dd], r);
    }

    // sh: h = i*16 + w*4 + (l>>4); 16-lane-group reduce -> global atomic
    #pragma unroll
    for (int i = 0; i < 4; ++i) {
        float r = acch[i];
        r += __shfl_xor(r, 1);
        r += __shfl_xor(r, 2);
        r += __shfl_xor(r, 4);
        r += __shfl_xor(r, 8);
        if ((l & 15) == 0) {
            const int h = i * 16 + w * 4 + (l >> 4);
            atomicAdd(&pool[(n * 192 + 64 + h) * 64 + c], r * (1.0f / 4096.0f));
        }
    }

    // sw: w = (l&15)*4 + j; combine lanes sharing w4 across the wave -> LDS
    #pragma unroll
    for (int j = 0; j < 4; ++j) {
        float r = accw[j];
        r += __shfl_down(r, 32);
        r += __shfl_down(r, 16);
        if (l < 16) atomicAdd(&swp[l * 4 + j], r);
    }
    __syncthreads();

    if (t < 16)   // d-slices d0..d0+15 are quarter-exclusive: plain store
        pool[(n * 192 + d0 + t) * 64 + c] = sdp[t] * (1.0f / 4096.0f);
    if (t < 64)
        atomicAdd(&pool[(n * 192 + 128 + t) * 64 + c], swp[t] * (1.0f / 4096.0f));
}

// Block b: cube blk = b>>2, quarter q = b&3. Gate chain recomputed per block
// (cheap); Stage C streams the quarter with nt load + nt store.
__global__ __launch_bounds__(256) void att_k(
    const float* __restrict__ x, const float* __restrict__ pool,
    const float* __restrict__ w1, const float* __restrict__ b1,
    const float* __restrict__ gam, const float* __restrict__ bet,
    const float* __restrict__ mu,  const float* __restrict__ var,
    const float* __restrict__ wd,  const float* __restrict__ bd,
    const float* __restrict__ wh,  const float* __restrict__ bh,
    const float* __restrict__ ww,  const float* __restrict__ bw,
    float* __restrict__ out)
{
    const int b   = blockIdx.x;
    const int blk = b >> 2;
    const int q   = b & 3;
    const int n = blk >> 6, c = blk & 63;
    const int d0 = q * 16;
    const int t = threadIdx.x;           // 0..255
    __shared__ float y_s[8][192];
    __shared__ float a_s[192];

    // ---- Stage A: y[m][l] = hardswish(BN(conv1(pool))) ----
    if (t < 192) {
        float acc[8] = {0,0,0,0,0,0,0,0};
        const f32x4* __restrict__ pp = (const f32x4*)(pool + (n * 192 + t) * 64);
        #pragma unroll 4
        for (int c4 = 0; c4 < 16; ++c4) {
            f32x4 p = pp[c4];
            const int cb = c4 * 4;
            #pragma unroll
            for (int m = 0; m < 8; ++m) {
                acc[m] += p.x * w1[m * 64 + cb]
                        + p.y * w1[m * 64 + cb + 1]
                        + p.z * w1[m * 64 + cb + 2]
                        + p.w * w1[m * 64 + cb + 3];
            }
        }
        #pragma unroll
        for (int m = 0; m < 8; ++m) {
            float scale = gam[m] * rsqrtf(var[m] + 1e-5f);
            float v = (acc[m] + b1[m] - mu[m]) * scale + bet[m];
            float hs = v * fminf(fmaxf(v + 3.0f, 0.0f), 6.0f) * (1.0f / 6.0f);
            y_s[m][t] = hs;
        }
    }
    __syncthreads();

    // ---- Stage B: gates a[l] = sigmoid(conv{d,h,w}(y)[o=c]) ----
    if (t < 192) {
        const float* wsel; float bsel;
        if (t < 64)       { wsel = wd + c * 8; bsel = bd[c]; }
        else if (t < 128) { wsel = wh + c * 8; bsel = bh[c]; }
        else              { wsel = ww + c * 8; bsel = bw[c]; }
        float v = bsel;
        #pragma unroll
        for (int m = 0; m < 8; ++m) v += y_s[m][t] * wsel[m];
        a_s[t] = 1.0f / (1.0f + __expf(-v));
    }
    __syncthreads();

    // ---- Stage C: out = x * ad*ah*aw over quarter d in [d0, d0+16) ----
    // f32x4 group p = i*256 + t within a slice: w4 = t&15 (i-invariant),
    // h = i*16 + (t>>4).
    const int w4 = t & 15;
    const int h4 = t >> 4;               // 0..15
    f32x4 gw;
    gw.x = a_s[128 + w4 * 4 + 0];
    gw.y = a_s[128 + w4 * 4 + 1];
    gw.z = a_s[128 + w4 * 4 + 2];
    gw.w = a_s[128 + w4 * 4 + 3];
    float ahr[4];
    #pragma unroll
    for (int i = 0; i < 4; ++i) ahr[i] = a_s[64 + i * 16 + h4];

    const f32x4* __restrict__ xp = (const f32x4*)(x   + (size_t)blk * 262144);
    f32x4*       __restrict__ op = (f32x4*)      (out + (size_t)blk * 262144);

    #pragma unroll
    for (int i = 0; i < 4; ++i) {
        #pragma unroll 2
        for (int dd = 0; dd < 16; ++dd) {
            const int off = (d0 + dd) * 1024 + i * 256 + t;
            const float s = a_s[d0 + dd] * ahr[i];
            f32x4 v = __builtin_nontemporal_load(&xp[off]);
            __builtin_nontemporal_store(v * (gw * s), &op[off]);
        }
    }
}

extern "C" void kernel_launch(void* const* d_in, const int* in_sizes, int n_in,
                              void* d_out, int out_size, void* d_ws, size_t ws_size,
                              hipStream_t stream) {
    const float* x = (const float*)d_in[0];
    float* pool = (float*)d_ws;   // 4*192*64 f32 = 192 KiB

    zero_k<<<48, 1024, 0, stream>>>(pool);          // 49152 floats
    pool_k<<<1024, 256, 0, stream>>>(x, pool);
    att_k<<<1024, 256, 0, stream>>>(x, pool,
        (const float*)d_in[1],  (const float*)d_in[2],
        (const float*)d_in[3],  (const float*)d_in[4],
        (const float*)d_in[5],  (const float*)d_in[6],
        (const float*)d_in[7],  (const float*)d_in[8],
        (const float*)d_in[9],  (const float*)d_in[10],
        (const float*)d_in[11], (const float*)d_in[12],
        (float*)d_out);
}